// Round 12
// baseline (81.109 us; speedup 1.0000x reference)
//
#include <hip/hip_runtime.h>
#include <math.h>

#define BB 8
#define CDIM 256
#define CCH 64
#define HDIM 64
#define WDIM 64
#define KJ 36           // S*S*K*K
#define EPSV 1e-5f

typedef __attribute__((ext_vector_type(8))) short bf16x8;
typedef __attribute__((ext_vector_type(4))) float f32x4;

__device__ inline unsigned short f2bf(float f) {
    unsigned int u = __float_as_uint(f);
    unsigned int r = (u + 0x7fffu + ((u >> 16) & 1u)) >> 16;
    return (unsigned short)r;
}
__device__ inline float bflo(unsigned int u) { return __uint_as_float(u << 16); }
__device__ inline float bfhi(unsigned int u) { return __uint_as_float(u & 0xffff0000u); }

// ---------------- K1: 1x1 conv via bf16 MFMA; comp packed bf16; fused w2 pack;
//                   transposed row-partials; XCD-swizzled ----------------
__global__ __launch_bounds__(256) void k1_mfma(const float* __restrict__ x,
                                               const float* __restrict__ w1,
                                               const float* __restrict__ b1,
                                               const float* __restrict__ w2,
                                               unsigned short* __restrict__ w2b,
                                               unsigned int* __restrict__ comp2,
                                               float* __restrict__ rowsum2,
                                               float* __restrict__ rowsq2) {
    __shared__ __align__(16) unsigned short xds[WDIM * CDIM];   // [w][c] bf16, swizzled, 32 KB
    const int bid = blockIdx.x;                 // 512 blocks, chunked XCD swizzle
    const int t = threadIdx.x;

    // folded w2 pack: blocks 0..107 each convert 256 elements (48*576 = 27648)
    {
        int i = bid * 256 + t;
        if (i < 48 * 576) {
            int j = i / 576, k = i % 576;
            int tap = k >> 6, o = k & 63;
            w2b[i] = (j < KJ) ? f2bf(w2[(size_t)(j * CCH + o) * 9 + tap]) : (unsigned short)0;
        }
    }

    const int logical = (bid & 7) * 64 + (bid >> 3);
    const int b = logical >> 6, h = logical & 63;
    const int lane = t & 63, wv = t >> 6;
    const int l15 = lane & 15, g = lane >> 4;

    // stage x[b,:,h,:] -> bf16 LDS [w][c], row stride 512 B, byte ^= (w&7)<<4
    const float* xr = x + ((size_t)b * CDIM) * (HDIM * WDIM) + (size_t)h * WDIM;
    const int wq = t & 15;
#pragma unroll
    for (int it = 0; it < 8; ++it) {
        int cp = (t >> 4) + it * 16;
        float4 a = *(const float4*)(xr + (size_t)(2 * cp) * (HDIM * WDIM) + wq * 4);
        float4 c = *(const float4*)(xr + (size_t)(2 * cp + 1) * (HDIM * WDIM) + wq * 4);
        float av[4] = {a.x, a.y, a.z, a.w};
        float cv[4] = {c.x, c.y, c.z, c.w};
#pragma unroll
        for (int i = 0; i < 4; ++i) {
            int w = wq * 4 + i;
            unsigned int d = (unsigned int)f2bf(av[i]) | ((unsigned int)f2bf(cv[i]) << 16);
            *(unsigned int*)((char*)xds + w * 512 + ((4 * cp) ^ ((w & 7) << 4))) = d;
        }
    }
    __syncthreads();

    // MFMA: wave wv owns o-tile [wv*16, +16); 4 px-tiles; K=256 in 8 steps
    f32x4 acc[4] = {};
    const int orow = wv * 16 + l15;
#pragma unroll
    for (int ks = 0; ks < 8; ++ks) {
        const float* wp = w1 + (size_t)orow * CDIM + ks * 32 + g * 8;
        float4 wa = *(const float4*)wp;
        float4 wb = *(const float4*)(wp + 4);
        bf16x8 afrag;
        afrag[0] = (short)f2bf(wa.x); afrag[1] = (short)f2bf(wa.y);
        afrag[2] = (short)f2bf(wa.z); afrag[3] = (short)f2bf(wa.w);
        afrag[4] = (short)f2bf(wb.x); afrag[5] = (short)f2bf(wb.y);
        afrag[6] = (short)f2bf(wb.z); afrag[7] = (short)f2bf(wb.w);
        int cb = ks * 64 + g * 16;
#pragma unroll
        for (int pt = 0; pt < 4; ++pt) {
            int wrow = pt * 16 + l15;
            bf16x8 bfrag = *(bf16x8*)((char*)xds + wrow * 512 + (cb ^ ((wrow & 7) << 4)));
            acc[pt] = __builtin_amdgcn_mfma_f32_16x16x32_bf16(afrag, bfrag, acc[pt], 0, 0, 0);
        }
    }

    // epilogue: D[o = wv*16 + g*4 + r][w = pt*16 + l15]; bias, packed-bf16 store, row stats
#pragma unroll
    for (int rp = 0; rp < 2; ++rp) {
        int o0 = wv * 16 + g * 4 + 2 * rp;
        int op = o0 >> 1;
        float bi0 = b1[o0], bi1 = b1[o0 + 1];
        float s0 = 0.f, q0 = 0.f, s1 = 0.f, q1 = 0.f;
#pragma unroll
        for (int pt = 0; pt < 4; ++pt) {
            float v0 = acc[pt][2 * rp] + bi0;
            float v1 = acc[pt][2 * rp + 1] + bi1;
            comp2[(((size_t)(b * HDIM + h)) * 32 + op) * 64 + pt * 16 + l15] =
                (unsigned int)f2bf(v0) | ((unsigned int)f2bf(v1) << 16);
            s0 += v0; q0 += v0 * v0; s1 += v1; q1 += v1 * v1;
        }
#pragma unroll
        for (int off = 1; off < 16; off <<= 1) {
            s0 += __shfl_xor(s0, off, 64);
            q0 += __shfl_xor(q0, off, 64);
            s1 += __shfl_xor(s1, off, 64);
            q1 += __shfl_xor(q1, off, 64);
        }
        if (l15 == 0) {
            *(float2*)&rowsum2[(size_t)logical * 64 + o0] = make_float2(s0, s1);
            *(float2*)&rowsq2[(size_t)logical * 64 + o0]  = make_float2(q0, q1);
        }
    }
}

// ---------------- K3: 2 output rows/block; inline BN-stats finalize + BN/ReLU +
//                   3x3 conv via bf16 MFMA; writes P = bf16(exp(enc)); XCD-swizzled ----------------
__global__ __launch_bounds__(512) void k3_mfma(const unsigned int* __restrict__ comp2,
                                               const float* __restrict__ rowsum2,
                                               const float* __restrict__ rowsq2,
                                               const float* __restrict__ gamma,
                                               const float* __restrict__ beta,
                                               const unsigned short* __restrict__ w2b,
                                               const float* __restrict__ b2,
                                               unsigned short* __restrict__ P) {
    __shared__ __align__(16) unsigned short cds[4 * 66 * CCH];  // [R=rr*66+wcol][o] bf16, 33.8 KB
    __shared__ float st[2 * CCH];
    __shared__ float redS[8][64], redQ[8][64];
    const int bid = blockIdx.x;                 // 256 blocks, chunked XCD swizzle
    const int logical = (bid & 7) * 32 + (bid >> 3);
    const int b = logical >> 5, hp = logical & 31;
    const int h0 = hp * 2;
    const int t = threadIdx.x;
    const int lane = t & 63, wv = t >> 6;       // 8 waves
    const int l15 = lane & 15, g = lane >> 4;

    // inline BN stats: coalesced reduce of transposed row partials (fixed order -> deterministic)
    {
        const int so = t & 63, part = t >> 6;   // 8 parts x 64 rows
        float s = 0.f, q = 0.f;
        for (int i = 0; i < 64; ++i) {
            int row = part * 64 + i;
            s += rowsum2[(size_t)row * 64 + so];
            q += rowsq2[(size_t)row * 64 + so];
        }
        redS[part][so] = s; redQ[part][so] = q;
    }
    __syncthreads();
    if (t < 64) {
        float S = 0.f, Q = 0.f;
#pragma unroll
        for (int i = 0; i < 8; ++i) { S += redS[i][t]; Q += redQ[i][t]; }
        const float N = (float)(BB * HDIM * WDIM);
        float mu = S / N;
        float var = Q / N - mu * mu;
        float a = rsqrtf(var + EPSV) * gamma[t];
        st[t] = a;
        st[CCH + t] = beta[t] - mu * a;
    }
    __syncthreads();

    // stage 4 comp rows (h0-1 .. h0+2) as bf16, layout [R=rr*66+wcol][o], swizzled
    for (int idx = t; idx < 4 * 32 * WDIM; idx += 512) {
        int rr = idx >> 11, rem = idx & 2047;
        int op = rem >> 6, w = rem & 63;
        int hh = h0 + rr - 1;
        unsigned int d = 0;
        if (hh >= 0 && hh < HDIM) {
            unsigned int u = comp2[(((size_t)(b * HDIM + hh)) * 32 + op) * 64 + w];
            int o0 = 2 * op;
            float v0 = fmaxf(bflo(u) * st[o0] + st[CCH + o0], 0.f);
            float v1 = fmaxf(bfhi(u) * st[o0 + 1] + st[CCH + o0 + 1], 0.f);
            d = (unsigned int)f2bf(v0) | ((unsigned int)f2bf(v1) << 16);
        }
        int R = rr * 66 + (w + 1);
        *(unsigned int*)((char*)cds + R * 128 + ((4 * op) ^ ((R & 7) << 4))) = d;
    }
    for (int idx = t; idx < 4 * 2 * 32; idx += 512) {
        int rr = idx >> 6, rem = idx & 63;
        int col = (rem >> 5) ? 65 : 0, op = rem & 31;
        int R = rr * 66 + col;
        *(unsigned int*)((char*)cds + R * 128 + ((4 * op) ^ ((R & 7) << 4))) = 0u;
    }
    __syncthreads();

    // implicit GEMM: waves 0-3 -> output row h0 (px-tiles 0-3), waves 4-7 -> h0+1
    f32x4 acc3[3] = {};
    const int pxl = wv * 16 + l15;              // 0..127
    const int hh = wv >> 2;                     // wave-uniform output sub-row
    const int wpx = pxl & 63;
#pragma unroll
    for (int ks = 0; ks < 18; ++ks) {
        int k0 = ks * 32 + g * 8;
        int dy = k0 / 192, rm = k0 % 192;
        int dx = rm >> 6, o0 = rm & 63;
        int R = (hh + dy) * 66 + wpx + dx;
        bf16x8 bfrag = *(bf16x8*)((char*)cds + R * 128 + ((2 * o0) ^ ((R & 7) << 4)));
#pragma unroll
        for (int jt = 0; jt < 3; ++jt) {
            int j = jt * 16 + l15;
            bf16x8 afrag = *(const bf16x8*)((const char*)w2b + (size_t)(j * 576 + k0) * 2);
            acc3[jt] = __builtin_amdgcn_mfma_f32_16x16x32_bf16(afrag, bfrag, acc3[jt], 0, 0, 0);
        }
    }
    const int hout = h0 + hh;
#pragma unroll
    for (int jt = 0; jt < 3; ++jt) {
#pragma unroll
        for (int r = 0; r < 4; ++r) {
            int j = jt * 16 + g * 4 + r;
            if (j < KJ) {
                float v = acc3[jt][r] + b2[j];
                P[(((size_t)(b * HDIM + hout)) * KJ + j) * 64 + wpx] = f2bf(__expf(v));
            }
        }
    }
}

// ---------------- K4: softmax denominator over H per (b,j,w) from bf16 P, u32 loads ----------------
__global__ __launch_bounds__(256) void k4_smstats(const unsigned short* __restrict__ P,
                                                  float* __restrict__ ivs) {
    const int bid = blockIdx.x;                 // 288 = 8*36
    const int b = bid & 7, j = bid >> 3;
    const int t = threadIdx.x;
    const int wp = t & 31, q = t >> 5;          // 8 h-groups of 8
    const unsigned int* P32 = (const unsigned int*)P;
    float s0 = 0.f, s1 = 0.f;
#pragma unroll
    for (int i = 0; i < 8; ++i) {
        int h = q * 8 + i;
        unsigned int u = P32[(((size_t)(b * HDIM + h)) * KJ + j) * 32 + wp];
        s0 += bflo(u); s1 += bfhi(u);
    }
    __shared__ float red[8][64];
    red[q][2 * wp] = s0; red[q][2 * wp + 1] = s1;
    __syncthreads();
    if (q == 0) {
        float a0 = 0.f, a1 = 0.f;
#pragma unroll
        for (int i = 0; i < 8; ++i) { a0 += red[i][2 * wp]; a1 += red[i][2 * wp + 1]; }
        *(float2*)&ivs[((size_t)b * KJ + j) * 64 + 2 * wp] = make_float2(1.f / a0, 1.f / a1);
    }
}

// ---------------- K5: CARAFE h-pair, 256 blocks x 1024 threads, XCD-swizzled ----------------
__global__ __launch_bounds__(1024) void k5_carafe(const float* __restrict__ x,
                                                  const unsigned short* __restrict__ P,
                                                  const float* __restrict__ ivs,
                                                  float* __restrict__ out) {
    __shared__ float ks2[2][KJ][WDIM];          // 18.4 KB
    const int bid = blockIdx.x;                 // 256 blocks, chunked XCD swizzle
    const int logical = (bid & 7) * 32 + (bid >> 3);
    const int b = logical >> 5;
    const int hp = logical & 31;                // h-pair 0..31
    const int h0 = hp * 2;
    const int t = threadIdx.x;

    const unsigned int* P32 = (const unsigned int*)P;
    for (int e = t; e < KJ * 32; e += 1024) {
        int j = e >> 5, wp = e & 31;
        float2 iv = *(const float2*)&ivs[((size_t)b * KJ + j) * 64 + 2 * wp];
        unsigned int u0 = P32[(((size_t)(b * HDIM + h0)) * KJ + j) * 32 + wp];
        unsigned int u1 = P32[(((size_t)(b * HDIM + h0 + 1)) * KJ + j) * 32 + wp];
        ks2[0][j][2 * wp]     = bflo(u0) * iv.x;
        ks2[0][j][2 * wp + 1] = bfhi(u0) * iv.y;
        ks2[1][j][2 * wp]     = bflo(u1) * iv.x;
        ks2[1][j][2 * wp + 1] = bfhi(u1) * iv.y;
    }
    __syncthreads();

    const int w = t & 63;
    const int grp = t >> 6;                     // 0..15: 16-channel group

    float kern[2][KJ];
#pragma unroll
    for (int hh = 0; hh < 2; ++hh)
#pragma unroll
        for (int j = 0; j < KJ; ++j) kern[hh][j] = ks2[hh][j][w];

    const int rm1 = (h0 > 0) ? h0 - 1 : 0;
    const int rp2 = (h0 + 2 < HDIM) ? h0 + 2 : HDIM - 1;
    const int wm1 = (w > 0) ? w - 1 : 0, wp1 = (w < 63) ? w + 1 : 63;

    for (int ci = 0; ci < 16; ++ci) {
        int c = grp * 16 + ci;
        const float* xb = x + ((size_t)b * CDIM + c) * (HDIM * WDIM);
        float r[4], tl[4], tr[4];
        r[0] = xb[rm1 * WDIM + w];
        r[1] = xb[h0 * WDIM + w];
        r[2] = xb[(h0 + 1) * WDIM + w];
        r[3] = xb[rp2 * WDIM + w];
#pragma unroll
        for (int i = 0; i < 4; ++i) {
            tl[i] = __shfl(r[i], wm1, 64);
            tr[i] = __shfl(r[i], wp1, 64);
        }

        int c2b = c >> 2;
        int codd = (c >> 1) & 1;
        int wsx = (c & 1) * 64 + w;
#pragma unroll
        for (int hh = 0; hh < 2; ++hh) {
            float o0 = 0.f, o1 = 0.f, o2 = 0.f, o3 = 0.f;
#pragma unroll
            for (int dy = 0; dy < 3; ++dy) {
                int rr = hh + dy;
                float a = tl[rr], m = r[rr], cc = tr[rr];
                int k = dy * 3;
                o0 += a * kern[hh][0 * 9 + k] + m * kern[hh][0 * 9 + k + 1] + cc * kern[hh][0 * 9 + k + 2];
                o1 += a * kern[hh][1 * 9 + k] + m * kern[hh][1 * 9 + k + 1] + cc * kern[hh][1 * 9 + k + 2];
                o2 += a * kern[hh][2 * 9 + k] + m * kern[hh][2 * 9 + k + 1] + cc * kern[hh][2 * 9 + k + 2];
                o3 += a * kern[hh][3 * 9 + k] + m * kern[hh][3 * 9 + k + 1] + cc * kern[hh][3 * 9 + k + 2];
            }
            // out[b, s*64 + c/4, 2h + ((c>>1)&1), (c&1)*64 + w]
            int hs = 2 * (h0 + hh) + codd;
            size_t base = ((size_t)b * CDIM) * (128 * 128) + (size_t)hs * 128 + wsx;
            __builtin_nontemporal_store(o0, &out[base + (size_t)(0 * 64 + c2b) * (128 * 128)]);
            __builtin_nontemporal_store(o1, &out[base + (size_t)(1 * 64 + c2b) * (128 * 128)]);
            __builtin_nontemporal_store(o2, &out[base + (size_t)(2 * 64 + c2b) * (128 * 128)]);
            __builtin_nontemporal_store(o3, &out[base + (size_t)(3 * 64 + c2b) * (128 * 128)]);
        }
    }
}

extern "C" void kernel_launch(void* const* d_in, const int* in_sizes, int n_in,
                              void* d_out, int out_size, void* d_ws, size_t ws_size,
                              hipStream_t stream) {
    const float* x     = (const float*)d_in[0];
    const float* w1    = (const float*)d_in[1];
    const float* b1    = (const float*)d_in[2];
    const float* gamma = (const float*)d_in[3];
    const float* beta  = (const float*)d_in[4];
    const float* w2    = (const float*)d_in[5];
    const float* b2    = (const float*)d_in[6];
    float* out = (float*)d_out;

    char* ws = (char*)d_ws;
    unsigned int* comp2 = (unsigned int*)(ws);                 // 4,194,304 B
    unsigned short* P   = (unsigned short*)(ws + 4194304);     // 2,359,296 -> 6,553,600
    float* ivs          = (float*)(ws + 6553600);              // 73,728 -> 6,627,328
    float* rowsum2      = (float*)(ws + 6627328);              // 131,072 -> 6,758,400
    float* rowsq2       = (float*)(ws + 6758400);              // 131,072 -> 6,889,472
    unsigned short* w2b = (unsigned short*)(ws + 6889472);     // 55,296 -> 6,944,768

    hipLaunchKernelGGL(k1_mfma,    dim3(BB * HDIM), dim3(256),  0, stream,
                       x, w1, b1, w2, w2b, comp2, rowsum2, rowsq2);
    hipLaunchKernelGGL(k3_mfma,    dim3(BB * 32),   dim3(512),  0, stream,
                       comp2, rowsum2, rowsq2, gamma, beta, w2b, b2, P);
    hipLaunchKernelGGL(k4_smstats, dim3(BB * KJ),   dim3(256),  0, stream, P, ivs);
    hipLaunchKernelGGL(k5_carafe,  dim3(BB * 32),   dim3(1024), 0, stream, x, P, ivs, out);
}

// Round 13
// 75.184 us; speedup vs baseline: 1.0788x; 1.0788x over previous
//
#include <hip/hip_runtime.h>
#include <math.h>

#define BB 8
#define CDIM 256
#define CCH 64
#define HDIM 64
#define WDIM 64
#define KJ 36           // S*S*K*K
#define EPSV 1e-5f

typedef __attribute__((ext_vector_type(8))) short bf16x8;
typedef __attribute__((ext_vector_type(4))) float f32x4;

__device__ inline unsigned short f2bf(float f) {
    unsigned int u = __float_as_uint(f);
    unsigned int r = (u + 0x7fffu + ((u >> 16) & 1u)) >> 16;
    return (unsigned short)r;
}
__device__ inline float bflo(unsigned int u) { return __uint_as_float(u << 16); }
__device__ inline float bfhi(unsigned int u) { return __uint_as_float(u & 0xffff0000u); }

// ---------------- K1: 1x1 conv via bf16 MFMA; comp packed bf16; fused w2 pack;
//                   transposed row-partials; XCD-swizzled ----------------
__global__ __launch_bounds__(256) void k1_mfma(const float* __restrict__ x,
                                               const float* __restrict__ w1,
                                               const float* __restrict__ b1,
                                               const float* __restrict__ w2,
                                               unsigned short* __restrict__ w2b,
                                               unsigned int* __restrict__ comp2,
                                               float* __restrict__ rowsum2,
                                               float* __restrict__ rowsq2) {
    __shared__ __align__(16) unsigned short xds[WDIM * CDIM];   // [w][c] bf16, swizzled, 32 KB
    const int bid = blockIdx.x;                 // 512 blocks, chunked XCD swizzle
    const int t = threadIdx.x;

    // folded w2 pack: blocks 0..107 each convert 256 elements (48*576 = 27648)
    {
        int i = bid * 256 + t;
        if (i < 48 * 576) {
            int j = i / 576, k = i % 576;
            int tap = k >> 6, o = k & 63;
            w2b[i] = (j < KJ) ? f2bf(w2[(size_t)(j * CCH + o) * 9 + tap]) : (unsigned short)0;
        }
    }

    const int logical = (bid & 7) * 64 + (bid >> 3);
    const int b = logical >> 6, h = logical & 63;
    const int lane = t & 63, wv = t >> 6;
    const int l15 = lane & 15, g = lane >> 4;

    // stage x[b,:,h,:] -> bf16 LDS [w][c], row stride 512 B, byte ^= (w&7)<<4
    const float* xr = x + ((size_t)b * CDIM) * (HDIM * WDIM) + (size_t)h * WDIM;
    const int wq = t & 15;
#pragma unroll
    for (int it = 0; it < 8; ++it) {
        int cp = (t >> 4) + it * 16;
        float4 a = *(const float4*)(xr + (size_t)(2 * cp) * (HDIM * WDIM) + wq * 4);
        float4 c = *(const float4*)(xr + (size_t)(2 * cp + 1) * (HDIM * WDIM) + wq * 4);
        float av[4] = {a.x, a.y, a.z, a.w};
        float cv[4] = {c.x, c.y, c.z, c.w};
#pragma unroll
        for (int i = 0; i < 4; ++i) {
            int w = wq * 4 + i;
            unsigned int d = (unsigned int)f2bf(av[i]) | ((unsigned int)f2bf(cv[i]) << 16);
            *(unsigned int*)((char*)xds + w * 512 + ((4 * cp) ^ ((w & 7) << 4))) = d;
        }
    }
    __syncthreads();

    // MFMA: wave wv owns o-tile [wv*16, +16); 4 px-tiles; K=256 in 8 steps
    f32x4 acc[4] = {};
    const int orow = wv * 16 + l15;
#pragma unroll
    for (int ks = 0; ks < 8; ++ks) {
        const float* wp = w1 + (size_t)orow * CDIM + ks * 32 + g * 8;
        float4 wa = *(const float4*)wp;
        float4 wb = *(const float4*)(wp + 4);
        bf16x8 afrag;
        afrag[0] = (short)f2bf(wa.x); afrag[1] = (short)f2bf(wa.y);
        afrag[2] = (short)f2bf(wa.z); afrag[3] = (short)f2bf(wa.w);
        afrag[4] = (short)f2bf(wb.x); afrag[5] = (short)f2bf(wb.y);
        afrag[6] = (short)f2bf(wb.z); afrag[7] = (short)f2bf(wb.w);
        int cb = ks * 64 + g * 16;
#pragma unroll
        for (int pt = 0; pt < 4; ++pt) {
            int wrow = pt * 16 + l15;
            bf16x8 bfrag = *(bf16x8*)((char*)xds + wrow * 512 + (cb ^ ((wrow & 7) << 4)));
            acc[pt] = __builtin_amdgcn_mfma_f32_16x16x32_bf16(afrag, bfrag, acc[pt], 0, 0, 0);
        }
    }

    // epilogue: D[o = wv*16 + g*4 + r][w = pt*16 + l15]; bias, packed-bf16 store, row stats
#pragma unroll
    for (int rp = 0; rp < 2; ++rp) {
        int o0 = wv * 16 + g * 4 + 2 * rp;
        int op = o0 >> 1;
        float bi0 = b1[o0], bi1 = b1[o0 + 1];
        float s0 = 0.f, q0 = 0.f, s1 = 0.f, q1 = 0.f;
#pragma unroll
        for (int pt = 0; pt < 4; ++pt) {
            float v0 = acc[pt][2 * rp] + bi0;
            float v1 = acc[pt][2 * rp + 1] + bi1;
            comp2[(((size_t)(b * HDIM + h)) * 32 + op) * 64 + pt * 16 + l15] =
                (unsigned int)f2bf(v0) | ((unsigned int)f2bf(v1) << 16);
            s0 += v0; q0 += v0 * v0; s1 += v1; q1 += v1 * v1;
        }
#pragma unroll
        for (int off = 1; off < 16; off <<= 1) {
            s0 += __shfl_xor(s0, off, 64);
            q0 += __shfl_xor(q0, off, 64);
            s1 += __shfl_xor(s1, off, 64);
            q1 += __shfl_xor(q1, off, 64);
        }
        if (l15 == 0) {
            *(float2*)&rowsum2[(size_t)logical * 64 + o0] = make_float2(s0, s1);
            *(float2*)&rowsq2[(size_t)logical * 64 + o0]  = make_float2(q0, q1);
        }
    }
}

// ---------------- K3: inline BN-stats finalize + BN/ReLU + 3x3 conv via bf16 MFMA;
//                   writes P = bf16(exp(enc)); XCD-swizzled (R11 version) ----------------
__global__ __launch_bounds__(256) void k3_mfma(const unsigned int* __restrict__ comp2,
                                               const float* __restrict__ rowsum2,
                                               const float* __restrict__ rowsq2,
                                               const float* __restrict__ gamma,
                                               const float* __restrict__ beta,
                                               const unsigned short* __restrict__ w2b,
                                               const float* __restrict__ b2,
                                               unsigned short* __restrict__ P) {
    __shared__ __align__(16) unsigned short cds[3 * 66 * CCH];  // [R=dy*66+wcol][o] bf16, 25 KB
    __shared__ float st[2 * CCH];
    __shared__ float redS[4][64], redQ[4][64];
    const int bid = blockIdx.x;                 // 512 blocks, chunked XCD swizzle
    const int logical = (bid & 7) * 64 + (bid >> 3);
    const int b = logical >> 6, h = logical & 63;
    const int t = threadIdx.x;
    const int lane = t & 63, wv = t >> 6;
    const int l15 = lane & 15, g = lane >> 4;

    // inline BN stats: coalesced reduce of transposed row partials (fixed order -> deterministic)
    {
        const int so = t & 63, part = t >> 6;
        float s = 0.f, q = 0.f;
        for (int i = 0; i < 128; ++i) {
            int row = part * 128 + i;
            s += rowsum2[(size_t)row * 64 + so];
            q += rowsq2[(size_t)row * 64 + so];
        }
        redS[part][so] = s; redQ[part][so] = q;
    }
    __syncthreads();
    if (t < 64) {
        float S = redS[0][t] + redS[1][t] + redS[2][t] + redS[3][t];
        float Q = redQ[0][t] + redQ[1][t] + redQ[2][t] + redQ[3][t];
        const float N = (float)(BB * HDIM * WDIM);
        float mu = S / N;
        float var = Q / N - mu * mu;
        float a = rsqrtf(var + EPSV) * gamma[t];
        st[t] = a;
        st[CCH + t] = beta[t] - mu * a;
    }
    __syncthreads();

    for (int idx = t; idx < 3 * 32 * WDIM; idx += 256) {
        int dy = idx >> 11, rem = idx & 2047;
        int op = rem >> 6, w = rem & 63;
        int hh = h + dy - 1;
        unsigned int d = 0;
        if (hh >= 0 && hh < HDIM) {
            unsigned int u = comp2[(((size_t)(b * HDIM + hh)) * 32 + op) * 64 + w];
            int o0 = 2 * op;
            float v0 = fmaxf(bflo(u) * st[o0] + st[CCH + o0], 0.f);
            float v1 = fmaxf(bfhi(u) * st[o0 + 1] + st[CCH + o0 + 1], 0.f);
            d = (unsigned int)f2bf(v0) | ((unsigned int)f2bf(v1) << 16);
        }
        int R = dy * 66 + (w + 1);
        *(unsigned int*)((char*)cds + R * 128 + ((4 * op) ^ ((R & 7) << 4))) = d;
    }
    for (int idx = t; idx < 3 * 2 * 32; idx += 256) {
        int dy = idx >> 6, rem = idx & 63;
        int col = (rem >> 5) ? 65 : 0, op = rem & 31;
        int R = dy * 66 + col;
        *(unsigned int*)((char*)cds + R * 128 + ((4 * op) ^ ((R & 7) << 4))) = 0u;
    }
    __syncthreads();

    f32x4 acc3[3] = {};
    const int px = wv * 16 + l15;
#pragma unroll
    for (int ks = 0; ks < 18; ++ks) {
        int k0 = ks * 32 + g * 8;
        int dy = k0 / 192, rm = k0 % 192;
        int dx = rm >> 6, o0 = rm & 63;
        int R = dy * 66 + px + dx;
        bf16x8 bfrag = *(bf16x8*)((char*)cds + R * 128 + ((2 * o0) ^ ((R & 7) << 4)));
#pragma unroll
        for (int jt = 0; jt < 3; ++jt) {
            int j = jt * 16 + l15;
            bf16x8 afrag = *(const bf16x8*)((const char*)w2b + (size_t)(j * 576 + k0) * 2);
            acc3[jt] = __builtin_amdgcn_mfma_f32_16x16x32_bf16(afrag, bfrag, acc3[jt], 0, 0, 0);
        }
    }
#pragma unroll
    for (int jt = 0; jt < 3; ++jt) {
#pragma unroll
        for (int r = 0; r < 4; ++r) {
            int j = jt * 16 + g * 4 + r;
            if (j < KJ) {
                float v = acc3[jt][r] + b2[j];
                P[(((size_t)(b * HDIM + h)) * KJ + j) * 64 + px] = f2bf(__expf(v));
            }
        }
    }
}

// ---------------- K5: fused softmax-denominator + CARAFE h-pair,
//                   256 blocks x 1024 threads, XCD-swizzled ----------------
__global__ __launch_bounds__(1024) void k5_carafe(const float* __restrict__ x,
                                                  const unsigned short* __restrict__ P,
                                                  float* __restrict__ out) {
    __shared__ float ks2[2][KJ][WDIM];          // 18.4 KB
    __shared__ float ivds[KJ][WDIM];            // 9.2 KB
    const int bid = blockIdx.x;                 // 256 blocks, chunked XCD swizzle
    const int logical = (bid & 7) * 32 + (bid >> 3);
    const int b = logical >> 5;
    const int hp = logical & 31;                // h-pair 0..31
    const int h0 = hp * 2;
    const int t = threadIdx.x;

    const unsigned int* P32 = (const unsigned int*)P;
    const unsigned int* Pb = P32 + ((size_t)b * HDIM) * (KJ * 32);

    // fused denominator: column-sum P over H for this batch (L2-hot, fixed order)
    for (int e = t; e < KJ * 32; e += 1024) {
        int j = e >> 5, wp = e & 31;
        const unsigned int* pc = Pb + (size_t)j * 32 + wp;
        float s0 = 0.f, s1 = 0.f;
#pragma unroll 8
        for (int h = 0; h < HDIM; ++h) {
            unsigned int u = pc[(size_t)h * (KJ * 32)];
            s0 += bflo(u); s1 += bfhi(u);
        }
        ivds[j][2 * wp] = 1.f / s0;
        ivds[j][2 * wp + 1] = 1.f / s1;
    }
    __syncthreads();

    for (int e = t; e < KJ * 32; e += 1024) {
        int j = e >> 5, wp = e & 31;
        unsigned int u0 = Pb[((size_t)h0 * KJ + j) * 32 + wp];
        unsigned int u1 = Pb[((size_t)(h0 + 1) * KJ + j) * 32 + wp];
        float i0 = ivds[j][2 * wp], i1 = ivds[j][2 * wp + 1];
        ks2[0][j][2 * wp]     = bflo(u0) * i0;
        ks2[0][j][2 * wp + 1] = bfhi(u0) * i1;
        ks2[1][j][2 * wp]     = bflo(u1) * i0;
        ks2[1][j][2 * wp + 1] = bfhi(u1) * i1;
    }
    __syncthreads();

    const int w = t & 63;
    const int grp = t >> 6;                     // 0..15: 16-channel group

    float kern[2][KJ];
#pragma unroll
    for (int hh = 0; hh < 2; ++hh)
#pragma unroll
        for (int j = 0; j < KJ; ++j) kern[hh][j] = ks2[hh][j][w];

    const int rm1 = (h0 > 0) ? h0 - 1 : 0;
    const int rp2 = (h0 + 2 < HDIM) ? h0 + 2 : HDIM - 1;
    const int wm1 = (w > 0) ? w - 1 : 0, wp1 = (w < 63) ? w + 1 : 63;

    for (int ci = 0; ci < 16; ++ci) {
        int c = grp * 16 + ci;
        const float* xb = x + ((size_t)b * CDIM + c) * (HDIM * WDIM);
        float r[4], tl[4], tr[4];
        r[0] = xb[rm1 * WDIM + w];
        r[1] = xb[h0 * WDIM + w];
        r[2] = xb[(h0 + 1) * WDIM + w];
        r[3] = xb[rp2 * WDIM + w];
#pragma unroll
        for (int i = 0; i < 4; ++i) {
            tl[i] = __shfl(r[i], wm1, 64);
            tr[i] = __shfl(r[i], wp1, 64);
        }

        int c2b = c >> 2;
        int codd = (c >> 1) & 1;
        int wsx = (c & 1) * 64 + w;
#pragma unroll
        for (int hh = 0; hh < 2; ++hh) {
            float o0 = 0.f, o1 = 0.f, o2 = 0.f, o3 = 0.f;
#pragma unroll
            for (int dy = 0; dy < 3; ++dy) {
                int rr = hh + dy;
                float a = tl[rr], m = r[rr], cc = tr[rr];
                int k = dy * 3;
                o0 += a * kern[hh][0 * 9 + k] + m * kern[hh][0 * 9 + k + 1] + cc * kern[hh][0 * 9 + k + 2];
                o1 += a * kern[hh][1 * 9 + k] + m * kern[hh][1 * 9 + k + 1] + cc * kern[hh][1 * 9 + k + 2];
                o2 += a * kern[hh][2 * 9 + k] + m * kern[hh][2 * 9 + k + 1] + cc * kern[hh][2 * 9 + k + 2];
                o3 += a * kern[hh][3 * 9 + k] + m * kern[hh][3 * 9 + k + 1] + cc * kern[hh][3 * 9 + k + 2];
            }
            // out[b, s*64 + c/4, 2h + ((c>>1)&1), (c&1)*64 + w]
            int hs = 2 * (h0 + hh) + codd;
            size_t base = ((size_t)b * CDIM) * (128 * 128) + (size_t)hs * 128 + wsx;
            __builtin_nontemporal_store(o0, &out[base + (size_t)(0 * 64 + c2b) * (128 * 128)]);
            __builtin_nontemporal_store(o1, &out[base + (size_t)(1 * 64 + c2b) * (128 * 128)]);
            __builtin_nontemporal_store(o2, &out[base + (size_t)(2 * 64 + c2b) * (128 * 128)]);
            __builtin_nontemporal_store(o3, &out[base + (size_t)(3 * 64 + c2b) * (128 * 128)]);
        }
    }
}

extern "C" void kernel_launch(void* const* d_in, const int* in_sizes, int n_in,
                              void* d_out, int out_size, void* d_ws, size_t ws_size,
                              hipStream_t stream) {
    const float* x     = (const float*)d_in[0];
    const float* w1    = (const float*)d_in[1];
    const float* b1    = (const float*)d_in[2];
    const float* gamma = (const float*)d_in[3];
    const float* beta  = (const float*)d_in[4];
    const float* w2    = (const float*)d_in[5];
    const float* b2    = (const float*)d_in[6];
    float* out = (float*)d_out;

    char* ws = (char*)d_ws;
    unsigned int* comp2 = (unsigned int*)(ws);                 // 4,194,304 B
    unsigned short* P   = (unsigned short*)(ws + 4194304);     // 2,359,296 -> 6,553,600
    float* rowsum2      = (float*)(ws + 6553600);              // 131,072 -> 6,684,672
    float* rowsq2       = (float*)(ws + 6684672);              // 131,072 -> 6,815,744
    unsigned short* w2b = (unsigned short*)(ws + 6815744);     // 55,296 -> 6,871,040

    hipLaunchKernelGGL(k1_mfma,   dim3(BB * HDIM), dim3(256),  0, stream,
                       x, w1, b1, w2, w2b, comp2, rowsum2, rowsq2);
    hipLaunchKernelGGL(k3_mfma,   dim3(BB * HDIM), dim3(256),  0, stream,
                       comp2, rowsum2, rowsq2, gamma, beta, w2b, b2, P);
    hipLaunchKernelGGL(k5_carafe, dim3(BB * 32),   dim3(1024), 0, stream, x, P, out);
}

// Round 14
// 71.265 us; speedup vs baseline: 1.1381x; 1.0550x over previous
//
#include <hip/hip_runtime.h>
#include <math.h>

#define BB 8
#define CDIM 256
#define CCH 64
#define HDIM 64
#define WDIM 64
#define KJ 36           // S*S*K*K
#define EPSV 1e-5f

typedef __attribute__((ext_vector_type(8))) short bf16x8;
typedef __attribute__((ext_vector_type(4))) float f32x4;

__device__ inline unsigned short f2bf(float f) {
    unsigned int u = __float_as_uint(f);
    unsigned int r = (u + 0x7fffu + ((u >> 16) & 1u)) >> 16;
    return (unsigned short)r;
}
__device__ inline float bflo(unsigned int u) { return __uint_as_float(u << 16); }
__device__ inline float bfhi(unsigned int u) { return __uint_as_float(u & 0xffff0000u); }

// ---------------- K1: 1x1 conv via bf16 MFMA; comp packed bf16; fused w2 pack;
//                   transposed row-partials; XCD-swizzled ----------------
__global__ __launch_bounds__(256) void k1_mfma(const float* __restrict__ x,
                                               const float* __restrict__ w1,
                                               const float* __restrict__ b1,
                                               const float* __restrict__ w2,
                                               unsigned short* __restrict__ w2b,
                                               unsigned int* __restrict__ comp2,
                                               float* __restrict__ rowsum2,
                                               float* __restrict__ rowsq2) {
    __shared__ __align__(16) unsigned short xds[WDIM * CDIM];   // [w][c] bf16, swizzled, 32 KB
    const int bid = blockIdx.x;                 // 512 blocks, chunked XCD swizzle
    const int t = threadIdx.x;

    // folded w2 pack: blocks 0..107 each convert 256 elements (48*576 = 27648)
    {
        int i = bid * 256 + t;
        if (i < 48 * 576) {
            int j = i / 576, k = i % 576;
            int tap = k >> 6, o = k & 63;
            w2b[i] = (j < KJ) ? f2bf(w2[(size_t)(j * CCH + o) * 9 + tap]) : (unsigned short)0;
        }
    }

    const int logical = (bid & 7) * 64 + (bid >> 3);
    const int b = logical >> 6, h = logical & 63;
    const int lane = t & 63, wv = t >> 6;
    const int l15 = lane & 15, g = lane >> 4;

    // stage x[b,:,h,:] -> bf16 LDS [w][c], row stride 512 B, byte ^= (w&7)<<4
    const float* xr = x + ((size_t)b * CDIM) * (HDIM * WDIM) + (size_t)h * WDIM;
    const int wq = t & 15;
#pragma unroll
    for (int it = 0; it < 8; ++it) {
        int cp = (t >> 4) + it * 16;
        float4 a = *(const float4*)(xr + (size_t)(2 * cp) * (HDIM * WDIM) + wq * 4);
        float4 c = *(const float4*)(xr + (size_t)(2 * cp + 1) * (HDIM * WDIM) + wq * 4);
        float av[4] = {a.x, a.y, a.z, a.w};
        float cv[4] = {c.x, c.y, c.z, c.w};
#pragma unroll
        for (int i = 0; i < 4; ++i) {
            int w = wq * 4 + i;
            unsigned int d = (unsigned int)f2bf(av[i]) | ((unsigned int)f2bf(cv[i]) << 16);
            *(unsigned int*)((char*)xds + w * 512 + ((4 * cp) ^ ((w & 7) << 4))) = d;
        }
    }
    __syncthreads();

    // MFMA: wave wv owns o-tile [wv*16, +16); 4 px-tiles; K=256 in 8 steps
    f32x4 acc[4] = {};
    const int orow = wv * 16 + l15;
#pragma unroll
    for (int ks = 0; ks < 8; ++ks) {
        const float* wp = w1 + (size_t)orow * CDIM + ks * 32 + g * 8;
        float4 wa = *(const float4*)wp;
        float4 wb = *(const float4*)(wp + 4);
        bf16x8 afrag;
        afrag[0] = (short)f2bf(wa.x); afrag[1] = (short)f2bf(wa.y);
        afrag[2] = (short)f2bf(wa.z); afrag[3] = (short)f2bf(wa.w);
        afrag[4] = (short)f2bf(wb.x); afrag[5] = (short)f2bf(wb.y);
        afrag[6] = (short)f2bf(wb.z); afrag[7] = (short)f2bf(wb.w);
        int cb = ks * 64 + g * 16;
#pragma unroll
        for (int pt = 0; pt < 4; ++pt) {
            int wrow = pt * 16 + l15;
            bf16x8 bfrag = *(bf16x8*)((char*)xds + wrow * 512 + (cb ^ ((wrow & 7) << 4)));
            acc[pt] = __builtin_amdgcn_mfma_f32_16x16x32_bf16(afrag, bfrag, acc[pt], 0, 0, 0);
        }
    }

    // epilogue: D[o = wv*16 + g*4 + r][w = pt*16 + l15]; bias, packed-bf16 store, row stats
#pragma unroll
    for (int rp = 0; rp < 2; ++rp) {
        int o0 = wv * 16 + g * 4 + 2 * rp;
        int op = o0 >> 1;
        float bi0 = b1[o0], bi1 = b1[o0 + 1];
        float s0 = 0.f, q0 = 0.f, s1 = 0.f, q1 = 0.f;
#pragma unroll
        for (int pt = 0; pt < 4; ++pt) {
            float v0 = acc[pt][2 * rp] + bi0;
            float v1 = acc[pt][2 * rp + 1] + bi1;
            comp2[(((size_t)(b * HDIM + h)) * 32 + op) * 64 + pt * 16 + l15] =
                (unsigned int)f2bf(v0) | ((unsigned int)f2bf(v1) << 16);
            s0 += v0; q0 += v0 * v0; s1 += v1; q1 += v1 * v1;
        }
#pragma unroll
        for (int off = 1; off < 16; off <<= 1) {
            s0 += __shfl_xor(s0, off, 64);
            q0 += __shfl_xor(q0, off, 64);
            s1 += __shfl_xor(s1, off, 64);
            q1 += __shfl_xor(q1, off, 64);
        }
        if (l15 == 0) {
            *(float2*)&rowsum2[(size_t)logical * 64 + o0] = make_float2(s0, s1);
            *(float2*)&rowsq2[(size_t)logical * 64 + o0]  = make_float2(q0, q1);
        }
    }
}

// ---------------- K3: inline BN-stats finalize + BN/ReLU + 3x3 conv via bf16 MFMA;
//                   writes P = bf16(exp(enc)); XCD-swizzled ----------------
__global__ __launch_bounds__(256) void k3_mfma(const unsigned int* __restrict__ comp2,
                                               const float* __restrict__ rowsum2,
                                               const float* __restrict__ rowsq2,
                                               const float* __restrict__ gamma,
                                               const float* __restrict__ beta,
                                               const unsigned short* __restrict__ w2b,
                                               const float* __restrict__ b2,
                                               unsigned short* __restrict__ P) {
    __shared__ __align__(16) unsigned short cds[3 * 66 * CCH];  // [R=dy*66+wcol][o] bf16, 25 KB
    __shared__ float st[2 * CCH];
    __shared__ float redS[4][64], redQ[4][64];
    const int bid = blockIdx.x;                 // 512 blocks, chunked XCD swizzle
    const int logical = (bid & 7) * 64 + (bid >> 3);
    const int b = logical >> 6, h = logical & 63;
    const int t = threadIdx.x;
    const int lane = t & 63, wv = t >> 6;
    const int l15 = lane & 15, g = lane >> 4;

    // inline BN stats: coalesced reduce of transposed row partials (fixed order -> deterministic)
    {
        const int so = t & 63, part = t >> 6;
        float s = 0.f, q = 0.f;
        for (int i = 0; i < 128; ++i) {
            int row = part * 128 + i;
            s += rowsum2[(size_t)row * 64 + so];
            q += rowsq2[(size_t)row * 64 + so];
        }
        redS[part][so] = s; redQ[part][so] = q;
    }
    __syncthreads();
    if (t < 64) {
        float S = redS[0][t] + redS[1][t] + redS[2][t] + redS[3][t];
        float Q = redQ[0][t] + redQ[1][t] + redQ[2][t] + redQ[3][t];
        const float N = (float)(BB * HDIM * WDIM);
        float mu = S / N;
        float var = Q / N - mu * mu;
        float a = rsqrtf(var + EPSV) * gamma[t];
        st[t] = a;
        st[CCH + t] = beta[t] - mu * a;
    }
    __syncthreads();

    for (int idx = t; idx < 3 * 32 * WDIM; idx += 256) {
        int dy = idx >> 11, rem = idx & 2047;
        int op = rem >> 6, w = rem & 63;
        int hh = h + dy - 1;
        unsigned int d = 0;
        if (hh >= 0 && hh < HDIM) {
            unsigned int u = comp2[(((size_t)(b * HDIM + hh)) * 32 + op) * 64 + w];
            int o0 = 2 * op;
            float v0 = fmaxf(bflo(u) * st[o0] + st[CCH + o0], 0.f);
            float v1 = fmaxf(bfhi(u) * st[o0 + 1] + st[CCH + o0 + 1], 0.f);
            d = (unsigned int)f2bf(v0) | ((unsigned int)f2bf(v1) << 16);
        }
        int R = dy * 66 + (w + 1);
        *(unsigned int*)((char*)cds + R * 128 + ((4 * op) ^ ((R & 7) << 4))) = d;
    }
    for (int idx = t; idx < 3 * 2 * 32; idx += 256) {
        int dy = idx >> 6, rem = idx & 63;
        int col = (rem >> 5) ? 65 : 0, op = rem & 31;
        int R = dy * 66 + col;
        *(unsigned int*)((char*)cds + R * 128 + ((4 * op) ^ ((R & 7) << 4))) = 0u;
    }
    __syncthreads();

    f32x4 acc3[3] = {};
    const int px = wv * 16 + l15;
#pragma unroll
    for (int ks = 0; ks < 18; ++ks) {
        int k0 = ks * 32 + g * 8;
        int dy = k0 / 192, rm = k0 % 192;
        int dx = rm >> 6, o0 = rm & 63;
        int R = dy * 66 + px + dx;
        bf16x8 bfrag = *(bf16x8*)((char*)cds + R * 128 + ((2 * o0) ^ ((R & 7) << 4)));
#pragma unroll
        for (int jt = 0; jt < 3; ++jt) {
            int j = jt * 16 + l15;
            bf16x8 afrag = *(const bf16x8*)((const char*)w2b + (size_t)(j * 576 + k0) * 2);
            acc3[jt] = __builtin_amdgcn_mfma_f32_16x16x32_bf16(afrag, bfrag, acc3[jt], 0, 0, 0);
        }
    }
#pragma unroll
    for (int jt = 0; jt < 3; ++jt) {
#pragma unroll
        for (int r = 0; r < 4; ++r) {
            int j = jt * 16 + g * 4 + r;
            if (j < KJ) {
                float v = acc3[jt][r] + b2[j];
                P[(((size_t)(b * HDIM + h)) * KJ + j) * 64 + px] = f2bf(__expf(v));
            }
        }
    }
}

// ---------------- K4: softmax denominator over H per (b,j,w) from bf16 P, u32 loads ----------------
__global__ __launch_bounds__(256) void k4_smstats(const unsigned short* __restrict__ P,
                                                  float* __restrict__ ivs) {
    const int bid = blockIdx.x;                 // 288 = 8*36
    const int b = bid & 7, j = bid >> 3;
    const int t = threadIdx.x;
    const int wp = t & 31, q = t >> 5;          // 8 h-groups of 8
    const unsigned int* P32 = (const unsigned int*)P;
    float s0 = 0.f, s1 = 0.f;
#pragma unroll
    for (int i = 0; i < 8; ++i) {
        int h = q * 8 + i;
        unsigned int u = P32[(((size_t)(b * HDIM + h)) * KJ + j) * 32 + wp];
        s0 += bflo(u); s1 += bfhi(u);
    }
    __shared__ float red[8][64];
    red[q][2 * wp] = s0; red[q][2 * wp + 1] = s1;
    __syncthreads();
    if (q == 0) {
        float a0 = 0.f, a1 = 0.f;
#pragma unroll
        for (int i = 0; i < 8; ++i) { a0 += red[i][2 * wp]; a1 += red[i][2 * wp + 1]; }
        *(float2*)&ivs[((size_t)b * KJ + j) * 64 + 2 * wp] = make_float2(1.f / a0, 1.f / a1);
    }
}

// ---------------- K5: CARAFE h-pair, 256 blocks x 1024 threads, XCD-swizzled ----------------
__global__ __launch_bounds__(1024) void k5_carafe(const float* __restrict__ x,
                                                  const unsigned short* __restrict__ P,
                                                  const float* __restrict__ ivs,
                                                  float* __restrict__ out) {
    __shared__ float ks2[2][KJ][WDIM];          // 18.4 KB
    const int bid = blockIdx.x;                 // 256 blocks, chunked XCD swizzle
    const int logical = (bid & 7) * 32 + (bid >> 3);
    const int b = logical >> 5;
    const int hp = logical & 31;                // h-pair 0..31
    const int h0 = hp * 2;
    const int t = threadIdx.x;

    const unsigned int* P32 = (const unsigned int*)P;
    for (int e = t; e < KJ * 32; e += 1024) {
        int j = e >> 5, wp = e & 31;
        float2 iv = *(const float2*)&ivs[((size_t)b * KJ + j) * 64 + 2 * wp];
        unsigned int u0 = P32[(((size_t)(b * HDIM + h0)) * KJ + j) * 32 + wp];
        unsigned int u1 = P32[(((size_t)(b * HDIM + h0 + 1)) * KJ + j) * 32 + wp];
        ks2[0][j][2 * wp]     = bflo(u0) * iv.x;
        ks2[0][j][2 * wp + 1] = bfhi(u0) * iv.y;
        ks2[1][j][2 * wp]     = bflo(u1) * iv.x;
        ks2[1][j][2 * wp + 1] = bfhi(u1) * iv.y;
    }
    __syncthreads();

    const int w = t & 63;
    const int grp = t >> 6;                     // 0..15: 16-channel group

    float kern[2][KJ];
#pragma unroll
    for (int hh = 0; hh < 2; ++hh)
#pragma unroll
        for (int j = 0; j < KJ; ++j) kern[hh][j] = ks2[hh][j][w];

    const int rm1 = (h0 > 0) ? h0 - 1 : 0;
    const int rp2 = (h0 + 2 < HDIM) ? h0 + 2 : HDIM - 1;
    const int wm1 = (w > 0) ? w - 1 : 0, wp1 = (w < 63) ? w + 1 : 63;

    for (int ci = 0; ci < 16; ++ci) {
        int c = grp * 16 + ci;
        const float* xb = x + ((size_t)b * CDIM + c) * (HDIM * WDIM);
        float r[4], tl[4], tr[4];
        r[0] = xb[rm1 * WDIM + w];
        r[1] = xb[h0 * WDIM + w];
        r[2] = xb[(h0 + 1) * WDIM + w];
        r[3] = xb[rp2 * WDIM + w];
#pragma unroll
        for (int i = 0; i < 4; ++i) {
            tl[i] = __shfl(r[i], wm1, 64);
            tr[i] = __shfl(r[i], wp1, 64);
        }

        int c2b = c >> 2;
        int codd = (c >> 1) & 1;
        int wsx = (c & 1) * 64 + w;
#pragma unroll
        for (int hh = 0; hh < 2; ++hh) {
            float o0 = 0.f, o1 = 0.f, o2 = 0.f, o3 = 0.f;
#pragma unroll
            for (int dy = 0; dy < 3; ++dy) {
                int rr = hh + dy;
                float a = tl[rr], m = r[rr], cc = tr[rr];
                int k = dy * 3;
                o0 += a * kern[hh][0 * 9 + k] + m * kern[hh][0 * 9 + k + 1] + cc * kern[hh][0 * 9 + k + 2];
                o1 += a * kern[hh][1 * 9 + k] + m * kern[hh][1 * 9 + k + 1] + cc * kern[hh][1 * 9 + k + 2];
                o2 += a * kern[hh][2 * 9 + k] + m * kern[hh][2 * 9 + k + 1] + cc * kern[hh][2 * 9 + k + 2];
                o3 += a * kern[hh][3 * 9 + k] + m * kern[hh][3 * 9 + k + 1] + cc * kern[hh][3 * 9 + k + 2];
            }
            // out[b, s*64 + c/4, 2h + ((c>>1)&1), (c&1)*64 + w]
            int hs = 2 * (h0 + hh) + codd;
            size_t base = ((size_t)b * CDIM) * (128 * 128) + (size_t)hs * 128 + wsx;
            __builtin_nontemporal_store(o0, &out[base + (size_t)(0 * 64 + c2b) * (128 * 128)]);
            __builtin_nontemporal_store(o1, &out[base + (size_t)(1 * 64 + c2b) * (128 * 128)]);
            __builtin_nontemporal_store(o2, &out[base + (size_t)(2 * 64 + c2b) * (128 * 128)]);
            __builtin_nontemporal_store(o3, &out[base + (size_t)(3 * 64 + c2b) * (128 * 128)]);
        }
    }
}

extern "C" void kernel_launch(void* const* d_in, const int* in_sizes, int n_in,
                              void* d_out, int out_size, void* d_ws, size_t ws_size,
                              hipStream_t stream) {
    const float* x     = (const float*)d_in[0];
    const float* w1    = (const float*)d_in[1];
    const float* b1    = (const float*)d_in[2];
    const float* gamma = (const float*)d_in[3];
    const float* beta  = (const float*)d_in[4];
    const float* w2    = (const float*)d_in[5];
    const float* b2    = (const float*)d_in[6];
    float* out = (float*)d_out;

    char* ws = (char*)d_ws;
    unsigned int* comp2 = (unsigned int*)(ws);                 // 4,194,304 B
    unsigned short* P   = (unsigned short*)(ws + 4194304);     // 2,359,296 -> 6,553,600
    float* ivs          = (float*)(ws + 6553600);              // 73,728 -> 6,627,328
    float* rowsum2      = (float*)(ws + 6627328);              // 131,072 -> 6,758,400
    float* rowsq2       = (float*)(ws + 6758400);              // 131,072 -> 6,889,472
    unsigned short* w2b = (unsigned short*)(ws + 6889472);     // 55,296 -> 6,944,768

    hipLaunchKernelGGL(k1_mfma,    dim3(BB * HDIM), dim3(256),  0, stream,
                       x, w1, b1, w2, w2b, comp2, rowsum2, rowsq2);
    hipLaunchKernelGGL(k3_mfma,    dim3(BB * HDIM), dim3(256),  0, stream,
                       comp2, rowsum2, rowsq2, gamma, beta, w2b, b2, P);
    hipLaunchKernelGGL(k4_smstats, dim3(BB * KJ),   dim3(256),  0, stream, P, ivs);
    hipLaunchKernelGGL(k5_carafe,  dim3(BB * 32),   dim3(1024), 0, stream, x, P, ivs, out);
}